// Round 1
// baseline (821.321 us; speedup 1.0000x reference)
//
#include <hip/hip_runtime.h>

#define NN 50000
#define NE 1600000
#define NTOT (NE + NN)        // edges + self loops
#define FDIM 128
#define CDIM 128              // H*D
#define NGRAPH 16
#define SLOPE 0.2f
#define SCAN_NB 196           // ceil(NN/256)

// ---------------- init: zero output, counts=1 (self loop), fill=0 ----------
__global__ __launch_bounds__(256) void k_init(float* __restrict__ out,
                                              int* __restrict__ counts,
                                              int* __restrict__ fill) {
    int i = blockIdx.x * 256 + threadIdx.x;
    if (i < NGRAPH * CDIM) out[i] = 0.f;
    if (i < NN) { counts[i] = 1; fill[i] = 0; }
}

// ---------------- fused transform: xl = x@Wl + bl, xr = x@Wr + br ----------
// block = 256 threads, 16 nodes per block (50000 = 3125 * 16 exact).
// thread: col c = tid&127, half = tid>>7 -> 8 nodes each, f-loop with
// LDS-broadcast x and L2-hot W columns (coalesced across lanes).
__global__ __launch_bounds__(256) void k_transform(
    const float* __restrict__ x,
    const float* __restrict__ Wl, const float* __restrict__ bl,
    const float* __restrict__ Wr, const float* __restrict__ br,
    float* __restrict__ xl, float* __restrict__ xr) {
    __shared__ float sx[FDIM][17];   // [f][node], padded: conflict-free writes
    const int node0 = blockIdx.x * 16;
    const int tid   = threadIdx.x;
    const int c     = tid & 127;
    const int half  = tid >> 7;

    for (int idx = tid; idx < 16 * FDIM; idx += 256) {
        int n = idx >> 7, f = idx & 127;
        sx[f][n] = x[(size_t)(node0 + n) * FDIM + f];
    }
    __syncthreads();

    float accl[8], accr[8];
#pragma unroll
    for (int k = 0; k < 8; k++) { accl[k] = 0.f; accr[k] = 0.f; }

    for (int f = 0; f < FDIM; f++) {
        float wl = Wl[f * CDIM + c];
        float wr = Wr[f * CDIM + c];
#pragma unroll
        for (int k = 0; k < 8; k++) {
            float xv = sx[f][half * 8 + k];   // wave-uniform -> LDS broadcast
            accl[k] += xv * wl;
            accr[k] += xv * wr;
        }
    }
    float blv = bl[c], brv = br[c];
#pragma unroll
    for (int k = 0; k < 8; k++) {
        int node = node0 + half * 8 + k;
        xl[(size_t)node * CDIM + c] = accl[k] + blv;
        xr[(size_t)node * CDIM + c] = accr[k] + brv;
    }
}

// ---------------- histogram of destinations ----------
__global__ __launch_bounds__(256) void k_hist(const int* __restrict__ dst,
                                              int* __restrict__ counts) {
    int e = blockIdx.x * 256 + threadIdx.x;
    if (e < NE) atomicAdd(&counts[dst[e]], 1);
}

// ---------------- exclusive scan (3-kernel two-level) ----------
__global__ __launch_bounds__(256) void k_scan1(const int* __restrict__ counts,
                                               int* __restrict__ offsets,
                                               int* __restrict__ bsums) {
    __shared__ int tmp[256];
    int t = threadIdx.x;
    int i = blockIdx.x * 256 + t;
    int v = (i < NN) ? counts[i] : 0;
    tmp[t] = v; __syncthreads();
    for (int off = 1; off < 256; off <<= 1) {
        int add = (t >= off) ? tmp[t - off] : 0;
        __syncthreads();
        tmp[t] += add;
        __syncthreads();
    }
    if (i < NN) offsets[i] = tmp[t] - v;         // exclusive
    if (t == 255) bsums[blockIdx.x] = tmp[255];  // block total
}

__global__ __launch_bounds__(256) void k_scan2(int* __restrict__ bsums) {
    __shared__ int tmp[256];
    int t = threadIdx.x;
    int v = (t < SCAN_NB) ? bsums[t] : 0;
    tmp[t] = v; __syncthreads();
    for (int off = 1; off < 256; off <<= 1) {
        int add = (t >= off) ? tmp[t - off] : 0;
        __syncthreads();
        tmp[t] += add;
        __syncthreads();
    }
    if (t < SCAN_NB) bsums[t] = tmp[t] - v;      // exclusive block offsets
}

__global__ __launch_bounds__(256) void k_scan3(int* __restrict__ offsets,
                                               const int* __restrict__ bsums) {
    int i = blockIdx.x * 256 + threadIdx.x;
    if (i < NN) offsets[i] += bsums[blockIdx.x];
}

// ---------------- scatter edges (+self loops) into CSR col[] ----------
__global__ __launch_bounds__(256) void k_scatter(const int* __restrict__ src,
                                                 const int* __restrict__ dst,
                                                 const int* __restrict__ offsets,
                                                 int* __restrict__ fill,
                                                 int* __restrict__ col) {
    int e = blockIdx.x * 256 + threadIdx.x;
    if (e >= NTOT) return;
    int s, d;
    if (e < NE) { s = src[e]; d = dst[e]; }
    else        { s = d = e - NE; }
    int pos = offsets[d] + atomicAdd(&fill[d], 1);
    col[pos] = s;
}

// ---------------- per-destination-node attention + aggregation + pool ------
// one wave per node; lane l owns channels {2l, 2l+1}; head h = lane>>4.
__global__ __launch_bounds__(256) void k_aggregate(
    const float* __restrict__ xl, const float* __restrict__ xr,
    const float* __restrict__ att, const float* __restrict__ bias,
    const int* __restrict__ batch,
    const int* __restrict__ offsets, const int* __restrict__ counts,
    const int* __restrict__ col, float* __restrict__ out) {
    const int wave = blockIdx.x * 4 + (threadIdx.x >> 6);
    const int lane = threadIdx.x & 63;
    if (wave >= NN) return;
    const int i     = wave;
    const int start = offsets[i];
    const int deg   = counts[i];

    const float2 rx = *(const float2*)&xr[(size_t)i * CDIM + lane * 2];
    const float2 a  = *(const float2*)&att[lane * 2];

    // pass 1: online softmax stats (exact max + sum)
    float m = -1e30f, s = 0.f;
    for (int base = 0; base < deg; base += 64) {
        int rem = deg - base;
        int cnt = rem < 64 ? rem : 64;
        int cj  = (lane < cnt) ? col[start + base + lane] : 0;
        for (int k = 0; k < cnt; k++) {
            int j = __shfl(cj, k);
            float2 v = *(const float2*)&xl[(size_t)j * CDIM + lane * 2];
            float t0 = v.x + rx.x, t1 = v.y + rx.y;
            t0 = fmaxf(t0, 0.f) + SLOPE * fminf(t0, 0.f);
            t1 = fmaxf(t1, 0.f) + SLOPE * fminf(t1, 0.f);
            float p = t0 * a.x + t1 * a.y;
            p += __shfl_xor(p, 1);
            p += __shfl_xor(p, 2);
            p += __shfl_xor(p, 4);
            p += __shfl_xor(p, 8);   // head-group (16 lanes) dot sum
            float nm = fmaxf(m, p);
            s = s * __expf(m - nm) + __expf(p - nm);
            m = nm;
        }
    }
    const float inv = 1.f / s;

    // pass 2: recompute logits, accumulate alpha * xl[j]
    float acc0 = 0.f, acc1 = 0.f;
    for (int base = 0; base < deg; base += 64) {
        int rem = deg - base;
        int cnt = rem < 64 ? rem : 64;
        int cj  = (lane < cnt) ? col[start + base + lane] : 0;
        for (int k = 0; k < cnt; k++) {
            int j = __shfl(cj, k);
            float2 v = *(const float2*)&xl[(size_t)j * CDIM + lane * 2];
            float t0 = v.x + rx.x, t1 = v.y + rx.y;
            t0 = fmaxf(t0, 0.f) + SLOPE * fminf(t0, 0.f);
            t1 = fmaxf(t1, 0.f) + SLOPE * fminf(t1, 0.f);
            float p = t0 * a.x + t1 * a.y;
            p += __shfl_xor(p, 1);
            p += __shfl_xor(p, 2);
            p += __shfl_xor(p, 4);
            p += __shfl_xor(p, 8);
            float alpha = __expf(p - m) * inv;
            acc0 += alpha * v.x;
            acc1 += alpha * v.y;
        }
    }

    // epilogue: +bias, ReLU, global max pool (nonneg float == int compare)
    float o0 = fmaxf(acc0 + bias[lane * 2], 0.f);
    float o1 = fmaxf(acc1 + bias[lane * 2 + 1], 0.f);
    int b = batch[i];
    atomicMax((int*)&out[b * CDIM + lane * 2],     __float_as_int(o0));
    atomicMax((int*)&out[b * CDIM + lane * 2 + 1], __float_as_int(o1));
}

extern "C" void kernel_launch(void* const* d_in, const int* in_sizes, int n_in,
                              void* d_out, int out_size, void* d_ws, size_t ws_size,
                              hipStream_t stream) {
    const float* x     = (const float*)d_in[0];
    const int*   ei    = (const int*)d_in[1];   // [2, NE]: row0=src, row1=dst
    const int*   batch = (const int*)d_in[2];
    const float* Wl    = (const float*)d_in[3];
    const float* bl    = (const float*)d_in[4];
    const float* Wr    = (const float*)d_in[5];
    const float* br    = (const float*)d_in[6];
    const float* att   = (const float*)d_in[7];
    const float* bias  = (const float*)d_in[8];
    float* out = (float*)d_out;

    char* w = (char*)d_ws;
    float* xl      = (float*)w; w += (size_t)NN * CDIM * 4;
    float* xr      = (float*)w; w += (size_t)NN * CDIM * 4;
    int*   counts  = (int*)w;   w += (size_t)NN * 4;
    int*   offsets = (int*)w;   w += (size_t)NN * 4;
    int*   fill    = (int*)w;   w += (size_t)NN * 4;
    int*   col     = (int*)w;   w += (size_t)NTOT * 4;
    int*   bsums   = (int*)w;   w += 256 * 4;

    const int* src = ei;
    const int* dst = ei + NE;

    k_init<<<SCAN_NB, 256, 0, stream>>>(out, counts, fill);
    k_transform<<<NN / 16, 256, 0, stream>>>(x, Wl, bl, Wr, br, xl, xr);
    k_hist<<<NE / 256, 256, 0, stream>>>(dst, counts);
    k_scan1<<<SCAN_NB, 256, 0, stream>>>(counts, offsets, bsums);
    k_scan2<<<1, 256, 0, stream>>>(bsums);
    k_scan3<<<SCAN_NB, 256, 0, stream>>>(offsets, bsums);
    k_scatter<<<(NTOT + 255) / 256, 256, 0, stream>>>(src, dst, offsets, fill, col);
    k_aggregate<<<NN / 4, 256, 0, stream>>>(xl, xr, att, bias, batch,
                                            offsets, counts, col, out);
}